// Round 5
// baseline (297.291 us; speedup 1.0000x reference)
//
#include <hip/hip_runtime.h>

#define KW   31
#define R    15
#define NP   32
#define HH   512
#define WW   512
#define NB   4

#define TX   16              // thread groups in x (each handles 4 consecutive px)
#define TY   16              // thread rows
#define PXW  (TX * 4)        // 64 pixels wide per block
#define EXT_Y (TY + 2*R)     // 46
#define EXT_X (PXW + 2*R)    // 94
#define SUBW 24              // sub-row width: x stored at pos 24*(x&3) + (x>>2)
#define XSTRIDE 104          // 4*SUBW + 8; ≡8 mod 32 -> wave rows at bank offsets {0,8,16,24}

__global__ __launch_bounds__(256, 2) void defocus_kernel(
    const float* __restrict__ sharp, const float* __restrict__ coc_map,
    float* __restrict__ out)
{
    __shared__ float gT[KW][NP];     // gT[tap][plane]
    __shared__ float bnd[KW];
    __shared__ float tile[3][EXT_Y][XSTRIDE];

    const int tid = threadIdx.x;

    // ---- per-plane 1-D Gaussian weights (zero-padded to 31, centered at R) ----
    if (tid < NP) {
        const int p = tid;
        const double step = 50.0 / 31.0;
        const float pv = (p == 31) ? 50.0f : (float)((double)p * step);
        #pragma unroll
        for (int j = 0; j < KW; ++j) gT[j][p] = 0.0f;
        if (pv < 0.5f) {
            gT[R][p] = 1.0f;
        } else {
            const double coc   = (double)pv;
            const double sigma = coc / 2.355;
            int k = (int)(2.0 * coc + 1.0);
            if ((k & 1) == 0) k += 1;
            if (k > KW) k = KW;
            const int half = k >> 1;
            float s = 0.0f;
            for (int j = 0; j < k; ++j) {
                double c = (double)(j - half);
                s += (float)exp(-(c * c) / (2.0 * sigma * sigma));
            }
            for (int j = 0; j < k; ++j) {
                double c = (double)(j - half);
                gT[R - half + j][p] = (float)exp(-(c * c) / (2.0 * sigma * sigma)) / s;
            }
        }
    }
    // ---- bucket boundaries, bit-exact float32((planes[i]+planes[i+1])/2) ----
    if (tid < KW) {
        const double step = 50.0 / 31.0;
        const float pa = (float)((double)tid * step);
        const float pb = (tid == 30) ? 50.0f : (float)((double)(tid + 1) * step);
        bnd[tid] = (pa + pb) * 0.5f;
    }

    // ---- stage input tile (+halo) with x-swizzle, zero outside image ----
    const int bx = blockIdx.x, by = blockIdx.y, bb = blockIdx.z;
    const int x0 = bx * PXW - R, y0 = by * TY - R;
    for (int idx = tid; idx < EXT_Y * EXT_X; idx += 256) {
        const int r = idx / EXT_X, c = idx - r * EXT_X;
        const int gy = y0 + r, gx = x0 + c;
        const bool ok = ((unsigned)gy < HH) && ((unsigned)gx < WW);
        const int pos = SUBW * (c & 3) + (c >> 2);
        #pragma unroll
        for (int ch = 0; ch < 3; ++ch) {
            tile[ch][r][pos] = ok ? sharp[(((size_t)bb * 3 + ch) * HH + gy) * WW + gx] : 0.0f;
        }
    }
    __syncthreads();

    // ---- this thread's 4 pixels ----
    const int tx = tid & (TX - 1), ty = tid >> 4;
    const int ox = bx * PXW + 4 * tx, oy = by * TY + ty;

    // plane select per pixel (exact reference semantics: count coc > bnd[k])
    const float4 coc4 = *(const float4*)&coc_map[((size_t)bb * HH + oy) * WW + ox];
    const float cocv[4] = {coc4.x, coc4.y, coc4.z, coc4.w};
    int plane[4];
    #pragma unroll
    for (int j = 0; j < 4; ++j) {
        int p = 0;
        #pragma unroll
        for (int k = 0; k < KW; ++k) p += (cocv[j] > bnd[k]) ? 1 : 0;
        plane[j] = p;
    }

    // per-pixel folded 1-D weights in REGISTERS (symmetric: 16 uniques);
    // used for BOTH x taps and y taps (same kernel)
    float gv[4][16];
    #pragma unroll
    for (int j = 0; j < 4; ++j)
        #pragma unroll
        for (int d = 0; d < 16; ++d) gv[j][d] = gT[R + d][plane[j]];

    // ---- separable accumulation; streamed swizzled window, all-constant indices ----
    #pragma unroll 1
    for (int ch = 0; ch < 3; ++ch) {
        float acc0 = 0.f, acc1 = 0.f, acc2 = 0.f, acc3 = 0.f;
        #pragma unroll
        for (int dy = 0; dy < KW; ++dy) {
            const float* rowp = &tile[ch][ty + dy][tx];
            float r0 = 0.f, r1 = 0.f, r2 = 0.f, r3 = 0.f;
            #pragma unroll
            for (int m = 0; m < 34; ++m) {
                const float w = rowp[SUBW * (m & 3) + (m >> 2)];
                if (m - 0 >= 0 && m - 0 <= 30) { const int d = (m - 15 >= 0) ? m - 15 : 15 - m; r0 = fmaf(gv[0][d], w, r0); }
                if (m - 1 >= 0 && m - 1 <= 30) { const int d = (m - 16 >= 0) ? m - 16 : 16 - m; r1 = fmaf(gv[1][d], w, r1); }
                if (m - 2 >= 0 && m - 2 <= 30) { const int d = (m - 17 >= 0) ? m - 17 : 17 - m; r2 = fmaf(gv[2][d], w, r2); }
                if (m - 3 >= 0 && m - 3 <= 30) { const int d = (m - 18 >= 0) ? m - 18 : 18 - m; r3 = fmaf(gv[3][d], w, r3); }
            }
            const int ady = (dy >= R) ? dy - R : R - dy;   // y-weight from registers
            acc0 = fmaf(gv[0][ady], r0, acc0);
            acc1 = fmaf(gv[1][ady], r1, acc1);
            acc2 = fmaf(gv[2][ady], r2, acc2);
            acc3 = fmaf(gv[3][ady], r3, acc3);
        }
        float4 o4 = make_float4(acc0, acc1, acc2, acc3);
        *(float4*)&out[(((size_t)bb * 3 + ch) * HH + oy) * WW + ox] = o4;
    }
}

extern "C" void kernel_launch(void* const* d_in, const int* in_sizes, int n_in,
                              void* d_out, int out_size, void* d_ws, size_t ws_size,
                              hipStream_t stream) {
    const float* sharp = (const float*)d_in[0];
    const float* coc   = (const float*)d_in[1];
    float* outp        = (float*)d_out;
    dim3 grid(WW / PXW, HH / TY, NB);
    defocus_kernel<<<grid, dim3(256), 0, stream>>>(sharp, coc, outp);
}

// Round 6
// 193.852 us; speedup vs baseline: 1.5336x; 1.5336x over previous
//
#include <hip/hip_runtime.h>

#define KW   31
#define R    15
#define NP   32
#define HH   512
#define WW   512
#define NB   4

#define TX   16              // thread groups in x (each handles 4 consecutive px)
#define TY   16              // thread rows
#define PXW  (TX * 4)        // 64 pixels wide per block
#define EXT_Y (TY + 2*R)     // 46
#define EXT_X (PXW + 2*R)    // 94
#define SUBW 24              // sub-row width: x stored at pos 24*(x&3) + (x>>2)
#define XSTRIDE 104          // 4*SUBW + 8; ≡8 mod 32 -> wave rows at bank offsets {0,8,16,24}

// launch_bounds(256,1): empirically (256,2) caps VGPR at 128 and forces scratch
// spill (R2/R5: 600MB scratch traffic). Occupancy is LDS-capped at 2 blocks/CU
// anyway (61.9KB), which needs only VGPR<=256 — so the loose bound is free.
__global__ __launch_bounds__(256, 1) void defocus_kernel(
    const float* __restrict__ sharp, const float* __restrict__ coc_map,
    float* __restrict__ out)
{
    __shared__ float gT[KW][NP];     // gT[tap][plane]
    __shared__ float bnd[KW];
    __shared__ float tile[3][EXT_Y][XSTRIDE];

    const int tid = threadIdx.x;

    // ---- per-plane 1-D Gaussian weights (zero-padded to 31, centered at R) ----
    if (tid < NP) {
        const int p = tid;
        const double step = 50.0 / 31.0;
        const float pv = (p == 31) ? 50.0f : (float)((double)p * step);
        #pragma unroll
        for (int j = 0; j < KW; ++j) gT[j][p] = 0.0f;
        if (pv < 0.5f) {
            gT[R][p] = 1.0f;
        } else {
            const double coc   = (double)pv;
            const double sigma = coc / 2.355;
            int k = (int)(2.0 * coc + 1.0);
            if ((k & 1) == 0) k += 1;
            if (k > KW) k = KW;
            const int half = k >> 1;
            float s = 0.0f;
            for (int j = 0; j < k; ++j) {
                double c = (double)(j - half);
                s += (float)exp(-(c * c) / (2.0 * sigma * sigma));
            }
            for (int j = 0; j < k; ++j) {
                double c = (double)(j - half);
                gT[R - half + j][p] = (float)exp(-(c * c) / (2.0 * sigma * sigma)) / s;
            }
        }
    }
    // ---- bucket boundaries, bit-exact float32((planes[i]+planes[i+1])/2) ----
    if (tid < KW) {
        const double step = 50.0 / 31.0;
        const float pa = (float)((double)tid * step);
        const float pb = (tid == 30) ? 50.0f : (float)((double)(tid + 1) * step);
        bnd[tid] = (pa + pb) * 0.5f;
    }

    // ---- stage input tile (+halo) with x-swizzle, zero outside image ----
    const int bx = blockIdx.x, by = blockIdx.y, bb = blockIdx.z;
    const int x0 = bx * PXW - R, y0 = by * TY - R;
    for (int idx = tid; idx < EXT_Y * EXT_X; idx += 256) {
        const int r = idx / EXT_X, c = idx - r * EXT_X;
        const int gy = y0 + r, gx = x0 + c;
        const bool ok = ((unsigned)gy < HH) && ((unsigned)gx < WW);
        const int pos = SUBW * (c & 3) + (c >> 2);
        #pragma unroll
        for (int ch = 0; ch < 3; ++ch) {
            tile[ch][r][pos] = ok ? sharp[(((size_t)bb * 3 + ch) * HH + gy) * WW + gx] : 0.0f;
        }
    }
    __syncthreads();

    // ---- this thread's 4 pixels ----
    const int tx = tid & (TX - 1), ty = tid >> 4;
    const int ox = bx * PXW + 4 * tx, oy = by * TY + ty;

    // plane select per pixel (exact reference semantics: count coc > bnd[k])
    const float4 coc4 = *(const float4*)&coc_map[((size_t)bb * HH + oy) * WW + ox];
    const float cocv[4] = {coc4.x, coc4.y, coc4.z, coc4.w};
    int plane[4];
    #pragma unroll
    for (int j = 0; j < 4; ++j) {
        int p = 0;
        #pragma unroll
        for (int k = 0; k < KW; ++k) p += (cocv[j] > bnd[k]) ? 1 : 0;
        plane[j] = p;
    }

    // per-pixel folded x-weights in REGISTERS (Gaussian symmetric: 16 uniques)
    float gv[4][16];
    #pragma unroll
    for (int j = 0; j < 4; ++j)
        #pragma unroll
        for (int d = 0; d < 16; ++d) gv[j][d] = gT[R + d][plane[j]];

    // ---- separable accumulation; streamed swizzled window ----
    #pragma unroll 1
    for (int ch = 0; ch < 3; ++ch) {
        float acc0 = 0.f, acc1 = 0.f, acc2 = 0.f, acc3 = 0.f;
        const float* rowp = &tile[ch][ty][tx];
        #pragma unroll 1
        for (int dy = 0; dy < KW; ++dy) {
            float r0 = 0.f, r1 = 0.f, r2 = 0.f, r3 = 0.f;
            #pragma unroll
            for (int m = 0; m < 34; ++m) {
                const float w = rowp[SUBW * (m & 3) + (m >> 2)];
                if (m - 0 >= 0 && m - 0 <= 30) { const int d = (m - 15 >= 0) ? m - 15 : 15 - m; r0 = fmaf(gv[0][d], w, r0); }
                if (m - 1 >= 0 && m - 1 <= 30) { const int d = (m - 16 >= 0) ? m - 16 : 16 - m; r1 = fmaf(gv[1][d], w, r1); }
                if (m - 2 >= 0 && m - 2 <= 30) { const int d = (m - 17 >= 0) ? m - 17 : 17 - m; r2 = fmaf(gv[2][d], w, r2); }
                if (m - 3 >= 0 && m - 3 <= 30) { const int d = (m - 18 >= 0) ? m - 18 : 18 - m; r3 = fmaf(gv[3][d], w, r3); }
            }
            // y-weight from LDS: avoids dynamic index into private gv (scratch!)
            acc0 = fmaf(gT[dy][plane[0]], r0, acc0);
            acc1 = fmaf(gT[dy][plane[1]], r1, acc1);
            acc2 = fmaf(gT[dy][plane[2]], r2, acc2);
            acc3 = fmaf(gT[dy][plane[3]], r3, acc3);
            rowp += XSTRIDE;
        }
        float4 o4 = make_float4(acc0, acc1, acc2, acc3);
        *(float4*)&out[(((size_t)bb * 3 + ch) * HH + oy) * WW + ox] = o4;
    }
}

extern "C" void kernel_launch(void* const* d_in, const int* in_sizes, int n_in,
                              void* d_out, int out_size, void* d_ws, size_t ws_size,
                              hipStream_t stream) {
    const float* sharp = (const float*)d_in[0];
    const float* coc   = (const float*)d_in[1];
    float* outp        = (float*)d_out;
    dim3 grid(WW / PXW, HH / TY, NB);
    defocus_kernel<<<grid, dim3(256), 0, stream>>>(sharp, coc, outp);
}

// Round 7
// 139.479 us; speedup vs baseline: 2.1314x; 1.3898x over previous
//
#include <hip/hip_runtime.h>

typedef _Float16 half_t;
typedef _Float16 half2_t __attribute__((ext_vector_type(2)));

#define KW   31
#define R    15
#define NP   32
#define HH   512
#define WW   512
#define NB   4

#define TX   16              // thread groups in x (each handles 4 consecutive px)
#define TY   16              // thread rows
#define PXW  (TX * 4)        // 64 pixels wide per block
#define EXT_Y (TY + 2*R)     // 46
#define EXT_X (PXW + 2*R)    // 94 pixels = 47 half2 dwords per row
#define DW_ROW 47            // used dwords per row
#define DSTRIDE 49           // half2 dwords per row; 49 mod 32 = 17 (odd) ->
                             // ty-rows alternate bank-parity classes, 2 lanes/bank = free

#if __has_builtin(__builtin_amdgcn_fdot2)
#define DOT2(a, b, c) __builtin_amdgcn_fdot2((a), (b), (c), false)
#else
#define DOT2(a, b, c) ((c) + (float)(a).x * (float)(b).x + (float)(a).y * (float)(b).y)
#endif

// (256,1): (256,2) empirically caps VGPR at 128 and spills (R2/R5).
__global__ __launch_bounds__(256, 1) void defocus_kernel(
    const float* __restrict__ sharp, const float* __restrict__ coc_map,
    float* __restrict__ out)
{
    __shared__ float gT[KW][NP];     // gT[tap][plane], f32 (row = 32 floats -> bank==plane)
    __shared__ float bnd[KW];
    __shared__ half2_t tile[3][EXT_Y][DSTRIDE];   // packed 2 px / dword, 27 KB

    const int tid = threadIdx.x;

    // ---- per-plane 1-D Gaussian weights (zero-padded to 31, centered at R) ----
    if (tid < NP) {
        const int p = tid;
        const double step = 50.0 / 31.0;
        const float pv = (p == 31) ? 50.0f : (float)((double)p * step);
        #pragma unroll
        for (int j = 0; j < KW; ++j) gT[j][p] = 0.0f;
        if (pv < 0.5f) {
            gT[R][p] = 1.0f;
        } else {
            const double coc   = (double)pv;
            const double sigma = coc / 2.355;
            int k = (int)(2.0 * coc + 1.0);
            if ((k & 1) == 0) k += 1;
            if (k > KW) k = KW;
            const int half = k >> 1;
            float s = 0.0f;
            for (int j = 0; j < k; ++j) {
                double c = (double)(j - half);
                s += (float)exp(-(c * c) / (2.0 * sigma * sigma));
            }
            for (int j = 0; j < k; ++j) {
                double c = (double)(j - half);
                gT[R - half + j][p] = (float)exp(-(c * c) / (2.0 * sigma * sigma)) / s;
            }
        }
    }
    // ---- bucket boundaries, bit-exact float32((planes[i]+planes[i+1])/2) ----
    if (tid < KW) {
        const double step = 50.0 / 31.0;
        const float pa = (float)((double)tid * step);
        const float pb = (tid == 30) ? 50.0f : (float)((double)(tid + 1) * step);
        bnd[tid] = (pa + pb) * 0.5f;
    }

    // ---- stage input tile (+halo) as packed f16 pairs, zero outside image ----
    const int bx = blockIdx.x, by = blockIdx.y, bb = blockIdx.z;
    const int x0 = bx * PXW - R, y0 = by * TY - R;
    for (int idx = tid; idx < EXT_Y * DW_ROW; idx += 256) {
        const int r = idx / DW_ROW, dw = idx - r * DW_ROW;
        const int gy = y0 + r;
        const int gxa = x0 + 2 * dw, gxb = gxa + 1;
        const bool oky = ((unsigned)gy < HH);
        #pragma unroll
        for (int ch = 0; ch < 3; ++ch) {
            const float* src = &sharp[(((size_t)bb * 3 + ch) * HH + gy) * WW];
            const float va = (oky && (unsigned)gxa < WW) ? src[gxa] : 0.0f;
            const float vb = (oky && (unsigned)gxb < WW) ? src[gxb] : 0.0f;
            half2_t h; h.x = (half_t)va; h.y = (half_t)vb;
            tile[ch][r][dw] = h;
        }
    }
    __syncthreads();

    // ---- this thread's 4 pixels ----
    const int tx = tid & (TX - 1), ty = tid >> 4;
    const int ox = bx * PXW + 4 * tx, oy = by * TY + ty;

    // plane select per pixel (exact reference semantics: count coc > bnd[k])
    const float4 coc4 = *(const float4*)&coc_map[((size_t)bb * HH + oy) * WW + ox];
    const float cocv[4] = {coc4.x, coc4.y, coc4.z, coc4.w};
    int plane[4];
    #pragma unroll
    for (int j = 0; j < 4; ++j) {
        int p = 0;
        #pragma unroll
        for (int k = 0; k < KW; ++k) p += (cocv[j] > bnd[k]) ? 1 : 0;
        plane[j] = p;
    }

    // ---- pre-pack per-pixel x-weights as half2 pairs matching data alignment ----
    // even px (0,2): pair i covers taps (2i, 2i+1); odd px (1,3): taps (2i-1, 2i).
    half2_t gwA0[16], gwB1[16], gwA2[16], gwB3[16];
    #pragma unroll
    for (int i = 0; i < 16; ++i) {
        half2_t a0, a2, b1, b3;
        a0.x = (half_t)gT[2 * i][plane[0]];
        a0.y = (i < 15) ? (half_t)gT[2 * i + 1][plane[0]] : (half_t)0.0f;
        a2.x = (half_t)gT[2 * i][plane[2]];
        a2.y = (i < 15) ? (half_t)gT[2 * i + 1][plane[2]] : (half_t)0.0f;
        b1.x = (i > 0) ? (half_t)gT[2 * i - 1][plane[1]] : (half_t)0.0f;
        b1.y = (half_t)gT[2 * i][plane[1]];
        b3.x = (i > 0) ? (half_t)gT[2 * i - 1][plane[3]] : (half_t)0.0f;
        b3.y = (half_t)gT[2 * i][plane[3]];
        gwA0[i] = a0; gwA2[i] = a2; gwB1[i] = b1; gwB3[i] = b3;
    }

    // ---- separable accumulation; 17 half2 window reads per (ch, dy) ----
    #pragma unroll 1
    for (int ch = 0; ch < 3; ++ch) {
        float acc0 = 0.f, acc1 = 0.f, acc2 = 0.f, acc3 = 0.f;
        const half2_t* rowp = &tile[ch][ty][2 * tx];
        #pragma unroll 1
        for (int dy = 0; dy < KW; ++dy) {
            float s0 = 0.f, s1 = 0.f, s2 = 0.f, s3 = 0.f;
            #pragma unroll
            for (int k = 0; k < 17; ++k) {
                const half2_t w = rowp[k];
                if (k < 16) { s0 = DOT2(w, gwA0[k], s0); s1 = DOT2(w, gwB1[k], s1); }
                if (k >= 1) { s2 = DOT2(w, gwA2[k - 1], s2); s3 = DOT2(w, gwB3[k - 1], s3); }
            }
            // y-weight from LDS (bank == plane -> broadcast/distinct-bank, free)
            acc0 = fmaf(gT[dy][plane[0]], s0, acc0);
            acc1 = fmaf(gT[dy][plane[1]], s1, acc1);
            acc2 = fmaf(gT[dy][plane[2]], s2, acc2);
            acc3 = fmaf(gT[dy][plane[3]], s3, acc3);
            rowp += DSTRIDE;
        }
        float4 o4 = make_float4(acc0, acc1, acc2, acc3);
        *(float4*)&out[(((size_t)bb * 3 + ch) * HH + oy) * WW + ox] = o4;
    }
}

extern "C" void kernel_launch(void* const* d_in, const int* in_sizes, int n_in,
                              void* d_out, int out_size, void* d_ws, size_t ws_size,
                              hipStream_t stream) {
    const float* sharp = (const float*)d_in[0];
    const float* coc   = (const float*)d_in[1];
    float* outp        = (float*)d_out;
    dim3 grid(WW / PXW, HH / TY, NB);
    defocus_kernel<<<grid, dim3(256), 0, stream>>>(sharp, coc, outp);
}